// Round 5
// baseline (715.937 us; speedup 1.0000x reference)
//
#include <hip/hip_runtime.h>
#include <cstddef>

#define LSLOPE 0.2f
#define BN_EPS 1e-5f

__device__ __forceinline__ float lrelu(float x) { return x > 0.f ? x : LSLOPE * x; }

using half4 = __attribute__((ext_vector_type(4))) _Float16;
using half8 = __attribute__((ext_vector_type(8))) _Float16;
using f32x4 = __attribute__((ext_vector_type(4))) float;

struct h2 { _Float16 h, l; };
__device__ __forceinline__ h2 split2h(float x) {
  h2 r;
  r.h = (_Float16)x;
  r.l = (_Float16)(x - (float)r.h);
  return r;
}

__device__ __forceinline__ unsigned short f2bf(float x) {
  unsigned u = __float_as_uint(x);
  unsigned r = (u + 0x7fffu + ((u >> 16) & 1u)) >> 16;
  return (unsigned short)r;
}
__device__ __forceinline__ float bflo(unsigned int u) { return __uint_as_float(u << 16); }
__device__ __forceinline__ float bfhi(unsigned int u) { return __uint_as_float(u & 0xffff0000u); }

// ---------- prep bodies ----------
// B-fragment layout: [kb][c][lane][8]  (kb-major) -> per-lane 16B at 16B stride,
// perfectly coalesced global reads in the GEMM K-loop.
__device__ __forceinline__ void bfrag_body(const float* __restrict__ B, _Float16* __restrict__ bh,
                                           _Float16* __restrict__ bl, int K, int M, int t) {
  int KB = K >> 5;
  int CTF = M >> 4;
  int lane = t & 63;
  int ckb  = t >> 6;
  int c  = ckb / KB, kb = ckb % KB;
  int mr = lane & 15, quad = lane >> 4;
  int col = c * 16 + mr;
  size_t obase = ((size_t)kb * CTF + c) * 512 + (size_t)lane * 8;
#pragma unroll
  for (int j = 0; j < 8; ++j) {
    int k = kb * 32 + quad * 8 + j;
    h2 s = split2h(B[(size_t)k * M + col]);
    bh[obase + j] = s.h;
    bl[obase + j] = s.l;
  }
}

__device__ __forceinline__ void matvec_body(const float* __restrict__ A, const float* __restrict__ v,
                                            float* __restrict__ out, int R, int K, int t) {
  int w = t >> 6;
  int lane = t & 63;
  if (w >= R) return;
  const float* row = A + (size_t)w * K;
  float s = 0.f;
  for (int k = lane; k < K; k += 64) s = fmaf(row[k], v[k], s);
#pragma unroll
  for (int off = 32; off; off >>= 1) s += __shfl_xor(s, off, 64);
  if (lane == 0) out[w] = s;
}

// one kernel: 3 B-frag splits + 4 fold-matvecs (block-range dispatch)
// wvs = W_src @ att_src so a_src = A @ wvs  (associativity-exact fold, same as a_dst)
__global__ __launch_bounds__(256) void prep_k(const float* __restrict__ W1s, const float* __restrict__ W2s,
                                              const float* __restrict__ fc1w,
                                              const float* __restrict__ W1d, const float* __restrict__ att1d,
                                              const float* __restrict__ W2d, const float* __restrict__ att2d,
                                              const float* __restrict__ att1s, const float* __restrict__ att2s,
                                              _Float16* B1h, _Float16* B1l, _Float16* B2h, _Float16* B2l,
                                              _Float16* Bfh, _Float16* Bfl,
                                              float* wvd1, float* wvd2, float* wvs1, float* wvs2) {
  int b = blockIdx.x;
  int tid = threadIdx.x;
  if (b < 16)       bfrag_body(W1s, B1h, B1l, 256, 128, b * 256 + tid);
  else if (b < 24)  bfrag_body(W2s, B2h, B2l, 128, 128, (b - 16) * 256 + tid);
  else if (b < 28)  bfrag_body(fc1w, Bfh, Bfl, 128, 64, (b - 24) * 256 + tid);
  else if (b < 92)  matvec_body(W1d, att1d, wvd1, 256, 128, (b - 28) * 256 + tid);
  else if (b < 124) matvec_body(W2d, att2d, wvd2, 128, 128, (b - 92) * 256 + tid);
  else if (b < 188) matvec_body(W1s, att1s, wvs1, 256, 128, (b - 124) * 256 + tid);
  else              matvec_body(W2s, att2s, wvs2, 128, 128, (b - 188) * 256 + tid);
}

// ---------- barrier-free K-loop GEMM: A tile staged ONCE (full K) in LDS ----------
// Four structures (r0/r1/r3/r4) all converged at ~85-90us: the per-K-step
// s_waitcnt vmcnt(0)+s_barrier convoy is the invariant (~8500 cyc/step measured
// top-down). Fix: stage the whole 64xK A tile once (coalesced 128B segments,
// XOR-swizzled 16B slots -> 2-way-max bank aliasing on read, free per m136),
// ONE __syncthreads, then a fully-unrolled K-loop with ZERO barriers:
// LDS is read-only (no race), B streams per-wave from L2 (kb-major fragment
// layout, per-lane 16B stride-16B = 1KB/instr coalesced). Compiler is free to
// software-pipeline loads across steps; waves never convoy.
template<int K, int MCOLS, bool PS>
__global__ __launch_bounds__(256) void gemm_nb(const float* __restrict__ Af,
                                               const _Float16* __restrict__ Ah,
                                               const _Float16* __restrict__ Al,
                                               const _Float16* __restrict__ Bh,
                                               const _Float16* __restrict__ Bl,
                                               float* __restrict__ Cf,
                                               unsigned short* __restrict__ Cbf,
                                               const float* __restrict__ wvs,
                                               float* __restrict__ asrc,
                                               const float* __restrict__ wvd,
                                               float* __restrict__ adout,
                                               int N,
                                               const float* __restrict__ bias) {
  constexpr int KB   = K / 32;
  constexpr int CTF  = MCOLS / 16;
  constexpr int HALF = MCOLS / 2;
  constexpr int CT   = HALF / 16;
  __shared__ __align__(16) _Float16 sAh[64 * K];
  __shared__ __align__(16) _Float16 sAl[64 * K];
  const int tid  = threadIdx.x;
  const int row0 = blockIdx.x * 64;
  const int wv   = tid >> 6;
  const int wm   = wv >> 1;
  const int wn   = wv & 1;
  const int lane = tid & 63;
  const int quad = lane >> 4;
  const int mr   = lane & 15;

  const float4 zf4 = make_float4(0.f, 0.f, 0.f, 0.f);
  const uint4  zu4 = make_uint4(0u, 0u, 0u, 0u);

  // ---- stage whole A tile (64 rows x K) once; XOR-swizzled 16B slots ----
  // thread t: row = t>>2; slots c8 = (t&3) + i*4  (lanes 0-3 cover 64B contig)
  {
    const int ar = tid >> 2;
    const int ac = tid & 3;
    const bool aok = (row0 + ar) < N;
#pragma unroll
    for (int i = 0; i < K / 32; ++i) {
      const int c8 = ac + i * 4;
      const int sx = c8 ^ (ar & 7);
      if (PS) {
        const size_t go = (size_t)(row0 + ar) * K + c8 * 8;
        uint4 uh = aok ? *(const uint4*)&Ah[go] : zu4;
        uint4 ul = aok ? *(const uint4*)&Al[go] : zu4;
        *(uint4*)&sAh[ar * K + sx * 8] = uh;
        *(uint4*)&sAl[ar * K + sx * 8] = ul;
      } else {
        const float* ap = &Af[(size_t)(row0 + ar) * K + c8 * 8];
        float4 f0 = aok ? *(const float4*)ap : zf4;
        float4 f1 = aok ? *(const float4*)(ap + 4) : zf4;
        h2 s0 = split2h(f0.x), s1 = split2h(f0.y), s2 = split2h(f0.z), s3 = split2h(f0.w);
        h2 s4 = split2h(f1.x), s5 = split2h(f1.y), s6 = split2h(f1.z), s7 = split2h(f1.w);
        half8 h, l;
        h[0] = s0.h; h[1] = s1.h; h[2] = s2.h; h[3] = s3.h;
        h[4] = s4.h; h[5] = s5.h; h[6] = s6.h; h[7] = s7.h;
        l[0] = s0.l; l[1] = s1.l; l[2] = s2.l; l[3] = s3.l;
        l[4] = s4.l; l[5] = s5.l; l[6] = s6.l; l[7] = s7.l;
        *(half8*)&sAh[ar * K + sx * 8] = h;
        *(half8*)&sAl[ar * K + sx * 8] = l;
      }
    }
  }
  __syncthreads();   // the ONLY barrier

  f32x4 acc[2][CT];
#pragma unroll
  for (int r = 0; r < 2; ++r)
#pragma unroll
    for (int c = 0; c < CT; ++c) acc[r][c] = (f32x4){0.f, 0.f, 0.f, 0.f};
  float pas[2] = {0.f, 0.f}, pad[2] = {0.f, 0.f};

  // ---- barrier-free fully-unrolled K-loop ----
#pragma unroll
  for (int kb = 0; kb < KB; ++kb) {
    const int kk = kb << 5;
    half8 ah[2], al[2];
#pragma unroll
    for (int r = 0; r < 2; ++r) {
      const int row = wm * 32 + r * 16 + mr;
      const int sx = (kb * 4 + quad) ^ (row & 7);
      ah[r] = *(const half8*)&sAh[row * K + sx * 8];
      al[r] = *(const half8*)&sAl[row * K + sx * 8];
    }
    if (wn == 0 && (wvs || wvd)) {   // fused row-dots vs folded att vectors
#pragma unroll
      for (int j = 0; j < 8; ++j) {
        const float vs = wvs ? wvs[kk + quad * 8 + j] : 0.f;
        const float vd = wvd ? wvd[kk + quad * 8 + j] : 0.f;
#pragma unroll
        for (int r = 0; r < 2; ++r) {
          const float av = (float)ah[r][j] + (float)al[r][j];
          if (wvs) pas[r] = fmaf(av, vs, pas[r]);
          if (wvd) pad[r] = fmaf(av, vd, pad[r]);
        }
      }
    }
#pragma unroll
    for (int c = 0; c < CT; ++c) {
      const size_t bo = ((size_t)kb * CTF + wn * CT + c) * 512 + (size_t)lane * 8;
      const half8 bh = *(const half8*)&Bh[bo];
      const half8 bl = *(const half8*)&Bl[bo];
#pragma unroll
      for (int r = 0; r < 2; ++r) {
        f32x4 a = acc[r][c];
        a = __builtin_amdgcn_mfma_f32_16x16x32_f16(al[r], bh, a, 0, 0, 0);
        a = __builtin_amdgcn_mfma_f32_16x16x32_f16(ah[r], bl, a, 0, 0, 0);
        a = __builtin_amdgcn_mfma_f32_16x16x32_f16(ah[r], bh, a, 0, 0, 0);
        acc[r][c] = a;
      }
    }
  }

  // epilogue: D col = lane&15, row = (lane>>4)*4 + reg  [m89/m91-verified]
#pragma unroll
  for (int r = 0; r < 2; ++r)
#pragma unroll
    for (int c = 0; c < CT; ++c) {
      const int gcol = wn * HALF + c * 16 + mr;
      const float bv = bias ? bias[gcol] : 0.f;
#pragma unroll
      for (int q = 0; q < 4; ++q) {
        const int grow = row0 + wm * 32 + r * 16 + quad * 4 + q;
        if (grow < N) {
          float val = acc[r][c][q] + bv;
          if (Cf)  Cf[(size_t)grow * MCOLS + gcol] = val;
          if (Cbf) Cbf[(size_t)grow * 128 + gcol] = f2bf(val);
        }
      }
    }
  if (wn == 0 && wvs) {
#pragma unroll
    for (int r = 0; r < 2; ++r) {
      float d = pas[r];
      d += __shfl_xor(d, 16, 64);
      d += __shfl_xor(d, 32, 64);
      const int grow = row0 + wm * 32 + r * 16 + mr;
      if (quad == 0 && grow < N) asrc[grow] = d;
    }
  }
  if (wn == 0 && wvd) {
#pragma unroll
    for (int r = 0; r < 2; ++r) {
      float d = pad[r];
      d += __shfl_xor(d, 16, 64);
      d += __shfl_xor(d, 32, 64);
      const int grow = row0 + wm * 32 + r * 16 + mr;
      if (quad == 0 && grow < N) adout[grow] = d;
    }
  }
}

// ---------------- CSR build ----------------
__global__ void deg_count_k(const int* __restrict__ edst, int E, int N, int* __restrict__ deg) {
  int i = blockIdx.x * 256 + threadIdx.x;
  if (i >= E + N) return;
  int d = (i < E) ? edst[i] : (i - E);
  atomicAdd(&deg[d], 1);
}

__global__ __launch_bounds__(1024) void scan1_k(const int* __restrict__ deg, int n,
                                                int* __restrict__ ex, int* __restrict__ bsum) {
  __shared__ int sm[1024];
  int t = threadIdx.x;
  int idx = blockIdx.x * 1024 + t;
  int v = (idx < n) ? deg[idx] : 0;
  sm[t] = v;
  __syncthreads();
  for (int off = 1; off < 1024; off <<= 1) {
    int tv = (t >= off) ? sm[t - off] : 0;
    __syncthreads();
    sm[t] += tv;
    __syncthreads();
  }
  if (idx < n) ex[idx] = sm[t] - v;
  if (t == 1023) bsum[blockIdx.x] = sm[t];
}

// scan3 with inlined block-sum prefix (scan2 eliminated): bsum holds RAW per-block sums.
__global__ void scan3_k(int* __restrict__ ex, const int* __restrict__ bsum, int n, int nb, int total,
                        int* __restrict__ cursor) {
  __shared__ int pbase[2];
  int idx = blockIdx.x * 256 + threadIdx.x;
  int bin0 = (blockIdx.x * 256) >> 10;
  if (threadIdx.x < 2) {
    int b = bin0 + threadIdx.x;
    int s = 0;
    for (int i = 0; i < b && i < nb; ++i) s += bsum[i];
    pbase[threadIdx.x] = s;
  }
  __syncthreads();
  if (idx < n) {
    int v = ex[idx] + pbase[(idx >> 10) - bin0];
    ex[idx] = v;
    cursor[idx] = v;
  }
  if (idx == 0) ex[n] = total;
}

// range-filtered scatter: only edges with dst in [d0,d1); write region fits L2, merges.
__global__ void scatter_range_k(const int* __restrict__ esrc, const int* __restrict__ edst,
                                int E, int N, int d0, int d1,
                                int* __restrict__ cursor, int* __restrict__ csr_src) {
  int i = blockIdx.x * 256 + threadIdx.x;
  if (i >= E + N) return;
  int d = (i < E) ? edst[i] : (i - E);
  if (d < d0 || d >= d1) return;
  int s = (i < E) ? esrc[i] : d;
  int pos = atomicAdd(&cursor[d], 1);
  csr_src[pos] = s;
}

// ---------------- GAT aggregation: wave/dst; quarter-wave uint4 gather, UNIFORM exec ----------------
__global__ __launch_bounds__(256) void gat_agg_k(const unsigned short* __restrict__ hbf,
                                                 const float* __restrict__ a_src,
                                                 const float* __restrict__ a_dst, const int* __restrict__ rowstart,
                                                 const int* __restrict__ csr_src, const float* __restrict__ bias,
                                                 _Float16* __restrict__ oh, _Float16* __restrict__ ol,
                                                 const float* __restrict__ wvd, float* __restrict__ ad_out,
                                                 int N) {
  int w = (blockIdx.x * blockDim.x + threadIdx.x) >> 6;
  int lane = threadIdx.x & 63;
  if (w >= N) return;
  int s0 = rowstart[w];
  int s1 = rowstart[w + 1];
  int deg = s1 - s0;
  float ad = a_dst[w];

  int sA = 0;
  float eA = -3.0e38f;
  if (lane < deg) {
    sA = csr_src[s0 + lane];
    eA = lrelu(a_src[sA] + ad);
  }
  float m = eA;
  for (int j = s0 + 64 + lane; j < s1; j += 64) {
    int s = csr_src[j];
    m = fmaxf(m, lrelu(a_src[s] + ad));
  }
#pragma unroll
  for (int off = 32; off; off >>= 1) m = fmaxf(m, __shfl_xor(m, off, 64));

  float preg = (lane < deg) ? __expf(eA - m) : 0.f;
  float den = preg;
  for (int j = s0 + 64 + lane; j < s1; j += 64) {
    int s = csr_src[j];
    den += __expf(lrelu(a_src[s] + ad) - m);
  }
#pragma unroll
  for (int off = 32; off; off >>= 1) den += __shfl_xor(den, off, 64);
  float inv = 1.f / den;

  // quarter-wave uint4 gather; bound padded to multiple of 4 => every __shfl at FULL exec
  // (divergent-exec shfl corrupted rounds 2/9). Padded edges carry preg=0.
  const int q  = lane >> 4;
  const int sl = lane & 15;
  const uint4* hrow4 = (const uint4*)hbf;
  float acc[8];
#pragma unroll
  for (int i = 0; i < 8; ++i) acc[i] = 0.f;

  int lim  = deg < 64 ? deg : 64;
  int lim4 = (lim + 3) & ~3;
  for (int jj = 0; jj < lim4; jj += 4) {
    int e = jj + q;
    int s = __shfl(sA, e, 64);
    float wgt = __shfl(preg, e, 64) * inv;
    uint4 u = hrow4[(size_t)s * 16 + sl];
    acc[0] = fmaf(wgt, bflo(u.x), acc[0]);
    acc[1] = fmaf(wgt, bfhi(u.x), acc[1]);
    acc[2] = fmaf(wgt, bflo(u.y), acc[2]);
    acc[3] = fmaf(wgt, bfhi(u.y), acc[3]);
    acc[4] = fmaf(wgt, bflo(u.z), acc[4]);
    acc[5] = fmaf(wgt, bfhi(u.z), acc[5]);
    acc[6] = fmaf(wgt, bflo(u.w), acc[6]);
    acc[7] = fmaf(wgt, bfhi(u.w), acc[7]);
  }
  for (int j = s0 + 64 + q; j < s1; j += 4) {  // rare deg>64 tail: shfl-free
    int s = csr_src[j];
    float wgt = __expf(lrelu(a_src[s] + ad) - m) * inv;
    uint4 u = hrow4[(size_t)s * 16 + sl];
    acc[0] = fmaf(wgt, bflo(u.x), acc[0]);
    acc[1] = fmaf(wgt, bfhi(u.x), acc[1]);
    acc[2] = fmaf(wgt, bflo(u.y), acc[2]);
    acc[3] = fmaf(wgt, bfhi(u.y), acc[3]);
    acc[4] = fmaf(wgt, bflo(u.z), acc[4]);
    acc[5] = fmaf(wgt, bfhi(u.z), acc[5]);
    acc[6] = fmaf(wgt, bflo(u.w), acc[6]);
    acc[7] = fmaf(wgt, bfhi(u.w), acc[7]);
  }
#pragma unroll
  for (int i = 0; i < 8; ++i) {
    acc[i] += __shfl_xor(acc[i], 16, 64);
    acc[i] += __shfl_xor(acc[i], 32, 64);
  }
  if (q == 0) {
    float4 b0 = *(const float4*)&bias[8 * sl];
    float4 b1 = *(const float4*)&bias[8 * sl + 4];
    float v[8];
    v[0] = fmaxf(acc[0] + b0.x, 0.f);
    v[1] = fmaxf(acc[1] + b0.y, 0.f);
    v[2] = fmaxf(acc[2] + b0.z, 0.f);
    v[3] = fmaxf(acc[3] + b0.w, 0.f);
    v[4] = fmaxf(acc[4] + b1.x, 0.f);
    v[5] = fmaxf(acc[5] + b1.y, 0.f);
    v[6] = fmaxf(acc[6] + b1.z, 0.f);
    v[7] = fmaxf(acc[7] + b1.w, 0.f);
    half8 vh, vl;
#pragma unroll
    for (int i = 0; i < 8; ++i) {
      h2 s = split2h(v[i]);
      vh[i] = s.h;
      vl[i] = s.l;
    }
    size_t base = (size_t)w * 128 + 8 * sl;
    *(half8*)&oh[base] = vh;
    *(half8*)&ol[base] = vl;
    if (wvd) {
      float4 w0 = *(const float4*)&wvd[8 * sl];
      float4 w1 = *(const float4*)&wvd[8 * sl + 4];
      float dd = v[0] * w0.x + v[1] * w0.y + v[2] * w0.z + v[3] * w0.w
               + v[4] * w1.x + v[5] * w1.y + v[6] * w1.z + v[7] * w1.w;
      dd += __shfl_xor(dd, 1, 64);
      dd += __shfl_xor(dd, 2, 64);
      dd += __shfl_xor(dd, 4, 64);
      dd += __shfl_xor(dd, 8, 64);
      if (sl == 0) ad_out[w] = dd;
    }
  }
}

// ---------------- BatchNorm stats ----------------
__global__ __launch_bounds__(256) void bn_stats_k(const float* __restrict__ z, int N,
                                                  float* __restrict__ sums, float* __restrict__ sumsq) {
  __shared__ float ls[256], lq[256];
  int col = threadIdx.x & 63;
  int rg = threadIdx.x >> 6;
  float s = 0.f, q = 0.f;
  for (int r = blockIdx.x * 4 + rg; r < N; r += gridDim.x * 4) {
    float v = z[(size_t)r * 64 + col];
    s += v;
    q = fmaf(v, v, q);
  }
  ls[threadIdx.x] = s;
  lq[threadIdx.x] = q;
  __syncthreads();
  if (threadIdx.x < 64) {
    s = ls[col] + ls[col + 64] + ls[col + 128] + ls[col + 192];
    q = lq[col] + lq[col + 64] + lq[col + 128] + lq[col + 192];
    atomicAdd(&sums[col], s);
    atomicAdd(&sumsq[col], q);
  }
}

// ---------------- fused BN-finalize + BN-apply + ReLU + FC2 + log_softmax ----------------
__global__ __launch_bounds__(256) void fc2_lsm_k(const float* __restrict__ z,
                                                 const float* __restrict__ sums, const float* __restrict__ sumsq,
                                                 const float* __restrict__ gamma, const float* __restrict__ beta,
                                                 const float* __restrict__ w,
                                                 const float* __restrict__ b, float* __restrict__ out,
                                                 int N, float invN) {
  __shared__ float ssc[64], ssh[64];
  if (threadIdx.x < 64) {
    int c = threadIdx.x;
    float mean = sums[c] * invN;
    float var = sumsq[c] * invN - mean * mean;
    float rs = rsqrtf(var + BN_EPS);
    float sc = gamma[c] * rs;
    ssc[c] = sc;
    ssh[c] = beta[c] - mean * sc;
  }
  __syncthreads();
  int n = blockIdx.x * 256 + threadIdx.x;
  if (n >= N) return;
  float o[40];
#pragma unroll
  for (int c = 0; c < 40; ++c) o[c] = b[c];
  const float* zr = z + (size_t)n * 64;
  for (int k = 0; k < 64; ++k) {
    float v = fmaxf(fmaf(zr[k], ssc[k], ssh[k]), 0.f);
#pragma unroll
    for (int c = 0; c < 40; ++c) o[c] = fmaf(v, w[k * 40 + c], o[c]);
  }
  float mx = o[0];
#pragma unroll
  for (int c = 1; c < 40; ++c) mx = fmaxf(mx, o[c]);
  float s = 0.f;
#pragma unroll
  for (int c = 0; c < 40; ++c) s += __expf(o[c] - mx);
  float ls = __logf(s);
  float* orow = out + (size_t)n * 40;
#pragma unroll
  for (int c = 0; c < 40; ++c) orow[c] = o[c] - mx - ls;
}

// ---------------- launch ----------------
static inline char* al16(char* p) { return (char*)(((size_t)p + 15) & ~(size_t)15); }

extern "C" void kernel_launch(void* const* d_in, const int* in_sizes, int n_in,
                              void* d_out, int out_size, void* d_ws, size_t ws_size,
                              hipStream_t stream) {
  const float* x     = (const float*)d_in[0];
  const int*   eidx  = (const int*)d_in[1];
  const float* W1s   = (const float*)d_in[2];
  const float* W1d   = (const float*)d_in[3];
  const float* att1s = (const float*)d_in[4];
  const float* att1d = (const float*)d_in[5];
  const float* b1    = (const float*)d_in[6];
  const float* W2s   = (const float*)d_in[7];
  const float* W2d   = (const float*)d_in[8];
  const float* att2s = (const float*)d_in[9];
  const float* att2d = (const float*)d_in[10];
  const float* b2    = (const float*)d_in[11];
  const float* fc1w  = (const float*)d_in[12];
  const float* fc1b  = (const float*)d_in[13];
  const float* gamma = (const float*)d_in[14];
  const float* beta  = (const float*)d_in[15];
  const float* fc2w  = (const float*)d_in[16];
  const float* fc2b  = (const float*)d_in[17];
  float* out = (float*)d_out;

  const int N  = in_sizes[0] / 256;
  const int E  = in_sizes[1] / 2;
  const int ET = E + N;

  // workspace layout — deg/sums/sumsq contiguous at front for a single memset
  char* p = (char*)d_ws;
  int* deg      = (int*)p;     p += (size_t)N * 4;
  float* sums   = (float*)p;   p += 64 * 4;
  float* sumsq  = (float*)p;   p += 64 * 4;
  unsigned short* bhA = (unsigned short*)p; p += (size_t)N * 128 * 2;
  _Float16* hAh = (_Float16*)p;  p += (size_t)N * 128 * 2;
  _Float16* hAl = (_Float16*)p;  p += (size_t)N * 128 * 2;
  float* hF = (float*)p;         p += (size_t)N * 64 * 4;
  int* rowstart = (int*)p;     p += (size_t)(N + 1) * 4;
  int* cursor   = (int*)p;     p += (size_t)N * 4;
  int* csr_src  = (int*)p;     p += (size_t)ET * 4;
  float* a_src  = (float*)p;   p += (size_t)N * 4;
  float* a_dst  = (float*)p;   p += (size_t)N * 4;
  float* a_dst2 = (float*)p;   p += (size_t)N * 4;
  float* wvd1   = (float*)p;   p += 256 * 4;
  float* wvd2   = (float*)p;   p += 128 * 4;
  float* wvs1   = (float*)p;   p += 256 * 4;
  float* wvs2   = (float*)p;   p += 128 * 4;
  int* bsum     = (int*)p;     p += 256 * 4;
  p = al16(p);
  _Float16* B1h = (_Float16*)p; p += (size_t)256 * 128 * 2;
  _Float16* B1l = (_Float16*)p; p += (size_t)256 * 128 * 2;
  _Float16* B2h = (_Float16*)p; p += (size_t)128 * 128 * 2;
  _Float16* B2l = (_Float16*)p; p += (size_t)128 * 128 * 2;
  _Float16* Bfh = (_Float16*)p; p += (size_t)128 * 64 * 2;
  _Float16* Bfl = (_Float16*)p; p += (size_t)128 * 64 * 2;

  const int* esrc = eidx;
  const int* edst = eidx + E;

  // one memset zeroes deg + sums + sumsq
  hipMemsetAsync(deg, 0, (size_t)N * 4 + 512, stream);

  deg_count_k<<<(ET + 255) / 256, 256, 0, stream>>>(edst, E, N, deg);
  int nb = (N + 1023) / 1024;
  scan1_k<<<nb, 1024, 0, stream>>>(deg, N, rowstart, bsum);
  scan3_k<<<(N + 255) / 256, 256, 0, stream>>>(rowstart, bsum, N, nb, ET, cursor);
  {
    const int NR = 8;
    int step = (N + NR - 1) / NR;
    for (int r = 0; r < NR; ++r) {
      int d0 = r * step;
      int d1 = d0 + step < N ? d0 + step : N;
      scatter_range_k<<<(ET + 255) / 256, 256, 0, stream>>>(esrc, edst, E, N, d0, d1, cursor, csr_src);
    }
  }

  // fused weight prep: 3 B-splits + 4 fold-matvecs in one dispatch
  prep_k<<<220, 256, 0, stream>>>(W1s, W2s, fc1w, W1d, att1d, W2d, att2d, att1s, att2s,
                                  B1h, B1l, B2h, B2l, Bfh, Bfl, wvd1, wvd2, wvs1, wvs2);

  const int gdk = (N + 63) / 64;

  // ---- GAT layer 1: barrier-free GEMM emits bf16 h + fused a_src (x.wvs1) + a_dst (x.wvd1) ----
  gemm_nb<256, 128, false><<<gdk, 256, 0, stream>>>(x, nullptr, nullptr, B1h, B1l,
                                                    nullptr, bhA, wvs1, a_src, wvd1, a_dst, N, nullptr);
  gat_agg_k<<<(N + 3) / 4, 256, 0, stream>>>(bhA, a_src, a_dst, rowstart, csr_src, b1,
                                             hAh, hAl, wvd2, a_dst2, N);

  // ---- GAT layer 2 (A pre-split f16; a_src2 = hA.wvs2 fused; a_dst2 fused in L1 agg) ----
  gemm_nb<128, 128, true><<<gdk, 256, 0, stream>>>(nullptr, hAh, hAl, B2h, B2l,
                                                   nullptr, bhA, wvs2, a_src, nullptr, nullptr, N, nullptr);
  gat_agg_k<<<(N + 3) / 4, 256, 0, stream>>>(bhA, a_src, a_dst2, rowstart, csr_src, b2,
                                             hAh, hAl, nullptr, nullptr, N);

  // ---- FC1 -> BN-stats -> fused BN+FC2+log_softmax ----
  gemm_nb<128, 64, true><<<gdk, 256, 0, stream>>>(nullptr, hAh, hAl, Bfh, Bfl,
                                                  hF, nullptr, nullptr, nullptr, nullptr, nullptr, N, fc1b);
  bn_stats_k<<<512, 256, 0, stream>>>(hF, N, sums, sumsq);
  fc2_lsm_k<<<(N + 255) / 256, 256, 0, stream>>>(hF, sums, sumsq, gamma, beta, fc2w, fc2b, out,
                                                 N, 1.0f / (float)N);
}

// Round 6
// 678.022 us; speedup vs baseline: 1.0559x; 1.0559x over previous
//
#include <hip/hip_runtime.h>
#include <cstddef>

#define LSLOPE 0.2f
#define BN_EPS 1e-5f

__device__ __forceinline__ float lrelu(float x) { return x > 0.f ? x : LSLOPE * x; }

using half4 = __attribute__((ext_vector_type(4))) _Float16;
using half8 = __attribute__((ext_vector_type(8))) _Float16;
using f32x4 = __attribute__((ext_vector_type(4))) float;

struct h2 { _Float16 h, l; };
__device__ __forceinline__ h2 split2h(float x) {
  h2 r;
  r.h = (_Float16)x;
  r.l = (_Float16)(x - (float)r.h);
  return r;
}

__device__ __forceinline__ unsigned short f2bf(float x) {
  unsigned u = __float_as_uint(x);
  unsigned r = (u + 0x7fffu + ((u >> 16) & 1u)) >> 16;
  return (unsigned short)r;
}
__device__ __forceinline__ float bflo(unsigned int u) { return __uint_as_float(u << 16); }
__device__ __forceinline__ float bfhi(unsigned int u) { return __uint_as_float(u & 0xffff0000u); }

// ---------- prep bodies ----------
// B-fragment layout: [kb][c][lane][8]  (kb-major) so one K-step's whole B slice
// (CTF*512 halfs) is contiguous -> global_load_lds-stageable in the GEMM.
__device__ __forceinline__ void bfrag_body(const float* __restrict__ B, _Float16* __restrict__ bh,
                                           _Float16* __restrict__ bl, int K, int M, int t) {
  int KB = K >> 5;
  int CTF = M >> 4;
  int lane = t & 63;
  int ckb  = t >> 6;
  int c  = ckb / KB, kb = ckb % KB;
  int mr = lane & 15, quad = lane >> 4;
  int col = c * 16 + mr;
  size_t obase = ((size_t)kb * CTF + c) * 512 + (size_t)lane * 8;
#pragma unroll
  for (int j = 0; j < 8; ++j) {
    int k = kb * 32 + quad * 8 + j;
    h2 s = split2h(B[(size_t)k * M + col]);
    bh[obase + j] = s.h;
    bl[obase + j] = s.l;
  }
}

__device__ __forceinline__ void matvec_body(const float* __restrict__ A, const float* __restrict__ v,
                                            float* __restrict__ out, int R, int K, int t) {
  int w = t >> 6;
  int lane = t & 63;
  if (w >= R) return;
  const float* row = A + (size_t)w * K;
  float s = 0.f;
  for (int k = lane; k < K; k += 64) s = fmaf(row[k], v[k], s);
#pragma unroll
  for (int off = 32; off; off >>= 1) s += __shfl_xor(s, off, 64);
  if (lane == 0) out[w] = s;
}

// one kernel: 3 B-frag splits + 4 fold-matvecs (block-range dispatch)
// wvs = W_src @ att_src so a_src = A @ wvs  (associativity-exact fold, same as a_dst)
__global__ __launch_bounds__(256) void prep_k(const float* __restrict__ W1s, const float* __restrict__ W2s,
                                              const float* __restrict__ fc1w,
                                              const float* __restrict__ W1d, const float* __restrict__ att1d,
                                              const float* __restrict__ W2d, const float* __restrict__ att2d,
                                              const float* __restrict__ att1s, const float* __restrict__ att2s,
                                              _Float16* B1h, _Float16* B1l, _Float16* B2h, _Float16* B2l,
                                              _Float16* Bfh, _Float16* Bfl,
                                              float* wvd1, float* wvd2, float* wvs1, float* wvs2) {
  int b = blockIdx.x;
  int tid = threadIdx.x;
  if (b < 16)       bfrag_body(W1s, B1h, B1l, 256, 128, b * 256 + tid);
  else if (b < 24)  bfrag_body(W2s, B2h, B2l, 128, 128, (b - 16) * 256 + tid);
  else if (b < 28)  bfrag_body(fc1w, Bfh, Bfl, 128, 64, (b - 24) * 256 + tid);
  else if (b < 92)  matvec_body(W1d, att1d, wvd1, 256, 128, (b - 28) * 256 + tid);
  else if (b < 124) matvec_body(W2d, att2d, wvd2, 128, 128, (b - 92) * 256 + tid);
  else if (b < 188) matvec_body(W1s, att1s, wvs1, 256, 128, (b - 124) * 256 + tid);
  else              matvec_body(W2s, att2s, wvs2, 128, 128, (b - 188) * 256 + tid);
}

// ---------- 64-row-tile LDS-staged 3-term f16 MFMA GEMM (round-4 best structure) ----------
// + T14 issue-early/write-late: A global load for step kb+2 is issued at step kb
// (named regs, no runtime-indexed arrays), so the LDS write of kb+1's data at the
// end of step kb uses a load that has had a FULL step to complete. The pre-barrier
// vmcnt(0) drain then only waits on the B DMA, not the A loads.
template<int K, int MCOLS, bool PS>
__global__ __launch_bounds__(256) void gemm_sk(const float* __restrict__ Af,
                                               const _Float16* __restrict__ Ah,
                                               const _Float16* __restrict__ Al,
                                               const _Float16* __restrict__ Bh,
                                               const _Float16* __restrict__ Bl,
                                               float* __restrict__ Cf,
                                               unsigned short* __restrict__ Cbf,
                                               const float* __restrict__ wvs,
                                               float* __restrict__ asrc,
                                               const float* __restrict__ wvd,
                                               float* __restrict__ adout,
                                               int N,
                                               const float* __restrict__ bias) {
  constexpr int KB   = K / 32;
  constexpr int HALF = MCOLS / 2;
  constexpr int CT   = HALF / 16;
  constexpr int CTF  = MCOLS / 16;    // total col-tiles
  constexpr int BCH  = CTF / 4;       // 1KB B-chunks per wave per h/l buffer
  __shared__ __align__(16) _Float16 sAh[2][64 * 32];
  __shared__ __align__(16) _Float16 sAl[2][64 * 32];
  __shared__ __align__(16) _Float16 sBh[2][CTF * 512];
  __shared__ __align__(16) _Float16 sBl[2][CTF * 512];
  const int tid  = threadIdx.x;
  const int row0 = blockIdx.x * 64;
  const int wv   = tid >> 6;
  const int wm   = wv >> 1;
  const int wn   = wv & 1;
  const int lane = tid & 63;
  const int quad = lane >> 4;
  const int mr   = lane & 15;

  f32x4 acc[2][CT];
#pragma unroll
  for (int r = 0; r < 2; ++r)
#pragma unroll
    for (int c = 0; c < CT; ++c) acc[r][c] = (f32x4){0.f, 0.f, 0.f, 0.f};
  float pas[2] = {0.f, 0.f}, pad[2] = {0.f, 0.f};

  // B staging: wave wv DMAs chunks [wv*BCH, wv*BCH+BCH) of the kb-slice.
  auto stage_b = [&](int buf, int kbs) {
    const size_t gb = (size_t)kbs * (CTF * 512) + (size_t)lane * 8;
#pragma unroll
    for (int pch = 0; pch < BCH; ++pch) {
      const int ch = wv * BCH + pch;
      __builtin_amdgcn_global_load_lds(
          (const __attribute__((address_space(1))) void*)(Bh + gb + (size_t)ch * 512),
          (__attribute__((address_space(3))) void*)&sBh[buf][ch * 512], 16, 0, 0);
      __builtin_amdgcn_global_load_lds(
          (const __attribute__((address_space(1))) void*)(Bl + gb + (size_t)ch * 512),
          (__attribute__((address_space(3))) void*)&sBl[buf][ch * 512], 16, 0, 0);
    }
  };

  // A staging addresses
  int srow, skc, soff;
  bool sok;
  if (PS) {
    srow = tid >> 2;              // 4 threads x 8 halves cover a 32-col row
    skc  = (tid & 3) << 3;
  } else {
    srow = tid >> 3;              // 8 threads x 4 floats cover a 32-col row
    skc  = (tid & 7) << 2;
  }
  soff = srow * 32 + ((skc + srow * 8) & 31);
  sok  = (row0 + srow) < N;
  int srow2 = 0, skc2 = 0, soff2 = 0;
  bool sok2 = false;
  if (!PS) {                      // second chunk for fp32 staging (512 quarters)
    int s = tid + 256;
    srow2 = s >> 3;
    skc2  = (s & 7) << 2;
    soff2 = srow2 * 32 + ((skc2 + srow2 * 8) & 31);
    sok2  = (row0 + srow2) < N;
  }

  const float4 zf4 = make_float4(0.f, 0.f, 0.f, 0.f);
  const uint4  zu4 = make_uint4(0u, 0u, 0u, 0u);

  stage_b(0, 0);

  // A(0): load and write straight into buffer 0
  {
    if (PS) {
      size_t go = (size_t)(row0 + srow) * K + skc;
      uint4 h0 = sok ? *(const uint4*)&Ah[go] : zu4;
      uint4 l0 = sok ? *(const uint4*)&Al[go] : zu4;
      *(uint4*)&sAh[0][soff] = h0;
      *(uint4*)&sAl[0][soff] = l0;
    } else {
      float4 f0 = sok  ? *(const float4*)&Af[(size_t)(row0 + srow) * K + skc]   : zf4;
      float4 f1 = sok2 ? *(const float4*)&Af[(size_t)(row0 + srow2) * K + skc2] : zf4;
      h2 s0 = split2h(f0.x), s1 = split2h(f0.y), s2 = split2h(f0.z), s3 = split2h(f0.w);
      half4 h4, l4;
      h4[0] = s0.h; h4[1] = s1.h; h4[2] = s2.h; h4[3] = s3.h;
      l4[0] = s0.l; l4[1] = s1.l; l4[2] = s2.l; l4[3] = s3.l;
      *(half4*)&sAh[0][soff] = h4;
      *(half4*)&sAl[0][soff] = l4;
      h2 t0 = split2h(f1.x), t1 = split2h(f1.y), t2 = split2h(f1.z), t3 = split2h(f1.w);
      h4[0] = t0.h; h4[1] = t1.h; h4[2] = t2.h; h4[3] = t3.h;
      l4[0] = t0.l; l4[1] = t1.l; l4[2] = t2.l; l4[3] = t3.l;
      *(half4*)&sAh[0][soff2] = h4;
      *(half4*)&sAl[0][soff2] = l4;
    }
  }

  // T14 prefetch registers: fa*/ua* hold A(kb+1) (to write this step);
  // fb*/ub* receive A(kb+2) (issued this step). Named regs only (rule #20).
  float4 fa0 = zf4, fa1 = zf4, fb0 = zf4, fb1 = zf4;
  uint4  uah = zu4, ual = zu4, ubh = zu4, ubl = zu4;
  if (KB > 1) {
    const int kn = 32;
    if (PS) {
      size_t go = (size_t)(row0 + srow) * K + kn + skc;
      uah = sok ? *(const uint4*)&Ah[go] : zu4;
      ual = sok ? *(const uint4*)&Al[go] : zu4;
    } else {
      fa0 = sok  ? *(const float4*)&Af[(size_t)(row0 + srow) * K + kn + skc]   : zf4;
      fa1 = sok2 ? *(const float4*)&Af[(size_t)(row0 + srow2) * K + kn + skc2] : zf4;
    }
  }
  __syncthreads();

  const size_t cstride = (size_t)KB * 512;

  for (int kb = 0; kb < KB; ++kb) {
    const int cur = kb & 1, nxt = cur ^ 1;
    const int kk = kb << 5;
    if (kb + 1 < KB) stage_b(nxt, kb + 1);   // B DMA 1-ahead (drained at barrier)
    if (kb + 2 < KB) {                        // A load 2-ahead (full step to land)
      const int kn = (kb + 2) << 5;
      if (PS) {
        size_t go = (size_t)(row0 + srow) * K + kn + skc;
        ubh = sok ? *(const uint4*)&Ah[go] : zu4;
        ubl = sok ? *(const uint4*)&Al[go] : zu4;
      } else {
        fb0 = sok  ? *(const float4*)&Af[(size_t)(row0 + srow) * K + kn + skc]   : zf4;
        fb1 = sok2 ? *(const float4*)&Af[(size_t)(row0 + srow2) * K + kn + skc2] : zf4;
      }
    }

    half8 ah[2], al[2];
#pragma unroll
    for (int r = 0; r < 2; ++r) {
      int row = wm * 32 + r * 16 + mr;
      int off = row * 32 + ((quad + row) & 3) * 8;
      ah[r] = *(const half8*)&sAh[cur][off];
      al[r] = *(const half8*)&sAl[cur][off];
    }
    if (wn == 0 && (wvs || wvd)) {   // fused row-dots vs folded att vectors
#pragma unroll
      for (int j = 0; j < 8; ++j) {
        const float vs = wvs ? wvs[kk + quad * 8 + j] : 0.f;
        const float vd = wvd ? wvd[kk + quad * 8 + j] : 0.f;
#pragma unroll
        for (int r = 0; r < 2; ++r) {
          const float av = (float)ah[r][j] + (float)al[r][j];
          if (wvs) pas[r] = fmaf(av, vs, pas[r]);
          if (wvd) pad[r] = fmaf(av, vd, pad[r]);
        }
      }
    }
#pragma unroll
    for (int c = 0; c < CT; ++c) {
      const half8 bh = *(const half8*)&sBh[cur][(wn * CT + c) * 512 + lane * 8];
      const half8 bl = *(const half8*)&sBl[cur][(wn * CT + c) * 512 + lane * 8];
#pragma unroll
      for (int r = 0; r < 2; ++r) {
        f32x4 a = acc[r][c];
        a = __builtin_amdgcn_mfma_f32_16x16x32_f16(al[r], bh, a, 0, 0, 0);
        a = __builtin_amdgcn_mfma_f32_16x16x32_f16(ah[r], bl, a, 0, 0, 0);
        a = __builtin_amdgcn_mfma_f32_16x16x32_f16(ah[r], bh, a, 0, 0, 0);
        acc[r][c] = a;
      }
    }
    if (kb + 1 < KB) {
      // write A(kb+1) from fa/ua (loaded a full step ago)
      if (PS) {
        *(uint4*)&sAh[nxt][soff] = uah;
        *(uint4*)&sAl[nxt][soff] = ual;
        uah = ubh; ual = ubl;                 // rotate
      } else {
        h2 s0 = split2h(fa0.x), s1 = split2h(fa0.y), s2 = split2h(fa0.z), s3 = split2h(fa0.w);
        half4 h4, l4;
        h4[0] = s0.h; h4[1] = s1.h; h4[2] = s2.h; h4[3] = s3.h;
        l4[0] = s0.l; l4[1] = s1.l; l4[2] = s2.l; l4[3] = s3.l;
        *(half4*)&sAh[nxt][soff] = h4;
        *(half4*)&sAl[nxt][soff] = l4;
        h2 t0 = split2h(fa1.x), t1 = split2h(fa1.y), t2 = split2h(fa1.z), t3 = split2h(fa1.w);
        h4[0] = t0.h; h4[1] = t1.h; h4[2] = t2.h; h4[3] = t3.h;
        l4[0] = t0.l; l4[1] = t1.l; l4[2] = t2.l; l4[3] = t3.l;
        *(half4*)&sAh[nxt][soff2] = h4;
        *(half4*)&sAl[nxt][soff2] = l4;
        fa0 = fb0; fa1 = fb1;                 // rotate
      }
    }
    __syncthreads();
  }

  // epilogue: D col = lane&15, row = (lane>>4)*4 + reg  [m89/m91-verified]
#pragma unroll
  for (int r = 0; r < 2; ++r)
#pragma unroll
    for (int c = 0; c < CT; ++c) {
      const int gcol = wn * HALF + c * 16 + mr;
      const float bv = bias ? bias[gcol] : 0.f;
#pragma unroll
      for (int q = 0; q < 4; ++q) {
        const int grow = row0 + wm * 32 + r * 16 + quad * 4 + q;
        if (grow < N) {
          float val = acc[r][c][q] + bv;
          if (Cf)  Cf[(size_t)grow * MCOLS + gcol] = val;
          if (Cbf) Cbf[(size_t)grow * 128 + gcol] = f2bf(val);
        }
      }
    }
  if (wn == 0 && wvs) {
#pragma unroll
    for (int r = 0; r < 2; ++r) {
      float d = pas[r];
      d += __shfl_xor(d, 16, 64);
      d += __shfl_xor(d, 32, 64);
      const int grow = row0 + wm * 32 + r * 16 + mr;
      if (quad == 0 && grow < N) asrc[grow] = d;
    }
  }
  if (wn == 0 && wvd) {
#pragma unroll
    for (int r = 0; r < 2; ++r) {
      float d = pad[r];
      d += __shfl_xor(d, 16, 64);
      d += __shfl_xor(d, 32, 64);
      const int grow = row0 + wm * 32 + r * 16 + mr;
      if (quad == 0 && grow < N) adout[grow] = d;
    }
  }
}

// ---------------- CSR build ----------------
__global__ void deg_count_k(const int* __restrict__ edst, int E, int N, int* __restrict__ deg) {
  int i = blockIdx.x * 256 + threadIdx.x;
  if (i >= E + N) return;
  int d = (i < E) ? edst[i] : (i - E);
  atomicAdd(&deg[d], 1);
}

__global__ __launch_bounds__(1024) void scan1_k(const int* __restrict__ deg, int n,
                                                int* __restrict__ ex, int* __restrict__ bsum) {
  __shared__ int sm[1024];
  int t = threadIdx.x;
  int idx = blockIdx.x * 1024 + t;
  int v = (idx < n) ? deg[idx] : 0;
  sm[t] = v;
  __syncthreads();
  for (int off = 1; off < 1024; off <<= 1) {
    int tv = (t >= off) ? sm[t - off] : 0;
    __syncthreads();
    sm[t] += tv;
    __syncthreads();
  }
  if (idx < n) ex[idx] = sm[t] - v;
  if (t == 1023) bsum[blockIdx.x] = sm[t];
}

// scan3 with inlined block-sum prefix (scan2 eliminated): bsum holds RAW per-block sums.
__global__ void scan3_k(int* __restrict__ ex, const int* __restrict__ bsum, int n, int nb, int total,
                        int* __restrict__ cursor) {
  __shared__ int pbase[2];
  int idx = blockIdx.x * 256 + threadIdx.x;
  int bin0 = (blockIdx.x * 256) >> 10;
  if (threadIdx.x < 2) {
    int b = bin0 + threadIdx.x;
    int s = 0;
    for (int i = 0; i < b && i < nb; ++i) s += bsum[i];
    pbase[threadIdx.x] = s;
  }
  __syncthreads();
  if (idx < n) {
    int v = ex[idx] + pbase[(idx >> 10) - bin0];
    ex[idx] = v;
    cursor[idx] = v;
  }
  if (idx == 0) ex[n] = total;
}

// range-filtered scatter: only edges with dst in [d0,d1); write region fits L2, merges.
__global__ void scatter_range_k(const int* __restrict__ esrc, const int* __restrict__ edst,
                                int E, int N, int d0, int d1,
                                int* __restrict__ cursor, int* __restrict__ csr_src) {
  int i = blockIdx.x * 256 + threadIdx.x;
  if (i >= E + N) return;
  int d = (i < E) ? edst[i] : (i - E);
  if (d < d0 || d >= d1) return;
  int s = (i < E) ? esrc[i] : d;
  int pos = atomicAdd(&cursor[d], 1);
  csr_src[pos] = s;
}

// ---------------- GAT aggregation: wave/dst; quarter-wave uint4 gather, UNIFORM exec ----------------
// T14 change: the main gather loop is software-pipelined depth-2 (issue iter j+1's
// shfl+uint4 load before consuming iter j) — converts serial load->use chains
// (~L3 latency each) into 2-in-flight. Loop bound lim4 is wave-uniform so every
// __shfl stays at FULL exec (the round-2/9 corruption hazard).
__global__ __launch_bounds__(256) void gat_agg_k(const unsigned short* __restrict__ hbf,
                                                 const float* __restrict__ a_src,
                                                 const float* __restrict__ a_dst, const int* __restrict__ rowstart,
                                                 const int* __restrict__ csr_src, const float* __restrict__ bias,
                                                 _Float16* __restrict__ oh, _Float16* __restrict__ ol,
                                                 const float* __restrict__ wvd, float* __restrict__ ad_out,
                                                 int N) {
  int w = (blockIdx.x * blockDim.x + threadIdx.x) >> 6;
  int lane = threadIdx.x & 63;
  if (w >= N) return;
  int s0 = rowstart[w];
  int s1 = rowstart[w + 1];
  int deg = s1 - s0;
  float ad = a_dst[w];

  int sA = 0;
  float eA = -3.0e38f;
  if (lane < deg) {
    sA = csr_src[s0 + lane];
    eA = lrelu(a_src[sA] + ad);
  }
  float m = eA;
  for (int j = s0 + 64 + lane; j < s1; j += 64) {
    int s = csr_src[j];
    m = fmaxf(m, lrelu(a_src[s] + ad));
  }
#pragma unroll
  for (int off = 32; off; off >>= 1) m = fmaxf(m, __shfl_xor(m, off, 64));

  float preg = (lane < deg) ? __expf(eA - m) : 0.f;
  float den = preg;
  for (int j = s0 + 64 + lane; j < s1; j += 64) {
    int s = csr_src[j];
    den += __expf(lrelu(a_src[s] + ad) - m);
  }
#pragma unroll
  for (int off = 32; off; off >>= 1) den += __shfl_xor(den, off, 64);
  float inv = 1.f / den;

  const int q  = lane >> 4;
  const int sl = lane & 15;
  const uint4* hrow4 = (const uint4*)hbf;
  float acc[8];
#pragma unroll
  for (int i = 0; i < 8; ++i) acc[i] = 0.f;

  int lim  = deg < 64 ? deg : 64;
  int lim4 = (lim + 3) & ~3;                 // >=4 always (self-loop => deg>=1)
  // prologue: preload iteration 0 (padded edges carry preg=0 -> wgt=0, sA=0 row is harmless)
  int   sP = __shfl(sA, q, 64);
  float wP = __shfl(preg, q, 64) * inv;
  uint4 uP = hrow4[(size_t)sP * 16 + sl];
  for (int jj = 4; jj < lim4; jj += 4) {
    int   sN = __shfl(sA, jj + q, 64);       // issue next iteration's load early
    float wN = __shfl(preg, jj + q, 64) * inv;
    uint4 uN = hrow4[(size_t)sN * 16 + sl];
    acc[0] = fmaf(wP, bflo(uP.x), acc[0]);
    acc[1] = fmaf(wP, bfhi(uP.x), acc[1]);
    acc[2] = fmaf(wP, bflo(uP.y), acc[2]);
    acc[3] = fmaf(wP, bfhi(uP.y), acc[3]);
    acc[4] = fmaf(wP, bflo(uP.z), acc[4]);
    acc[5] = fmaf(wP, bfhi(uP.z), acc[5]);
    acc[6] = fmaf(wP, bflo(uP.w), acc[6]);
    acc[7] = fmaf(wP, bfhi(uP.w), acc[7]);
    uP = uN; wP = wN;
  }
  acc[0] = fmaf(wP, bflo(uP.x), acc[0]);
  acc[1] = fmaf(wP, bfhi(uP.x), acc[1]);
  acc[2] = fmaf(wP, bflo(uP.y), acc[2]);
  acc[3] = fmaf(wP, bfhi(uP.y), acc[3]);
  acc[4] = fmaf(wP, bflo(uP.z), acc[4]);
  acc[5] = fmaf(wP, bfhi(uP.z), acc[5]);
  acc[6] = fmaf(wP, bflo(uP.w), acc[6]);
  acc[7] = fmaf(wP, bfhi(uP.w), acc[7]);

  for (int j = s0 + 64 + q; j < s1; j += 4) {  // rare deg>64 tail: shfl-free
    int s = csr_src[j];
    float wgt = __expf(lrelu(a_src[s] + ad) - m) * inv;
    uint4 u = hrow4[(size_t)s * 16 + sl];
    acc[0] = fmaf(wgt, bflo(u.x), acc[0]);
    acc[1] = fmaf(wgt, bfhi(u.x), acc[1]);
    acc[2] = fmaf(wgt, bflo(u.y), acc[2]);
    acc[3] = fmaf(wgt, bfhi(u.y), acc[3]);
    acc[4] = fmaf(wgt, bflo(u.z), acc[4]);
    acc[5] = fmaf(wgt, bfhi(u.z), acc[5]);
    acc[6] = fmaf(wgt, bflo(u.w), acc[6]);
    acc[7] = fmaf(wgt, bfhi(u.w), acc[7]);
  }
#pragma unroll
  for (int i = 0; i < 8; ++i) {
    acc[i] += __shfl_xor(acc[i], 16, 64);
    acc[i] += __shfl_xor(acc[i], 32, 64);
  }
  if (q == 0) {
    float4 b0 = *(const float4*)&bias[8 * sl];
    float4 b1 = *(const float4*)&bias[8 * sl + 4];
    float v[8];
    v[0] = fmaxf(acc[0] + b0.x, 0.f);
    v[1] = fmaxf(acc[1] + b0.y, 0.f);
    v[2] = fmaxf(acc[2] + b0.z, 0.f);
    v[3] = fmaxf(acc[3] + b0.w, 0.f);
    v[4] = fmaxf(acc[4] + b1.x, 0.f);
    v[5] = fmaxf(acc[5] + b1.y, 0.f);
    v[6] = fmaxf(acc[6] + b1.z, 0.f);
    v[7] = fmaxf(acc[7] + b1.w, 0.f);
    half8 vh, vl;
#pragma unroll
    for (int i = 0; i < 8; ++i) {
      h2 s = split2h(v[i]);
      vh[i] = s.h;
      vl[i] = s.l;
    }
    size_t base = (size_t)w * 128 + 8 * sl;
    *(half8*)&oh[base] = vh;
    *(half8*)&ol[base] = vl;
    if (wvd) {
      float4 w0 = *(const float4*)&wvd[8 * sl];
      float4 w1 = *(const float4*)&wvd[8 * sl + 4];
      float dd = v[0] * w0.x + v[1] * w0.y + v[2] * w0.z + v[3] * w0.w
               + v[4] * w1.x + v[5] * w1.y + v[6] * w1.z + v[7] * w1.w;
      dd += __shfl_xor(dd, 1, 64);
      dd += __shfl_xor(dd, 2, 64);
      dd += __shfl_xor(dd, 4, 64);
      dd += __shfl_xor(dd, 8, 64);
      if (sl == 0) ad_out[w] = dd;
    }
  }
}

// ---------------- BatchNorm stats ----------------
__global__ __launch_bounds__(256) void bn_stats_k(const float* __restrict__ z, int N,
                                                  float* __restrict__ sums, float* __restrict__ sumsq) {
  __shared__ float ls[256], lq[256];
  int col = threadIdx.x & 63;
  int rg = threadIdx.x >> 6;
  float s = 0.f, q = 0.f;
  for (int r = blockIdx.x * 4 + rg; r < N; r += gridDim.x * 4) {
    float v = z[(size_t)r * 64 + col];
    s += v;
    q = fmaf(v, v, q);
  }
  ls[threadIdx.x] = s;
  lq[threadIdx.x] = q;
  __syncthreads();
  if (threadIdx.x < 64) {
    s = ls[col] + ls[col + 64] + ls[col + 128] + ls[col + 192];
    q = lq[col] + lq[col + 64] + lq[col + 128] + lq[col + 192];
    atomicAdd(&sums[col], s);
    atomicAdd(&sumsq[col], q);
  }
}

// ---------------- fused BN-finalize + BN-apply + ReLU + FC2 + log_softmax ----------------
__global__ __launch_bounds__(256) void fc2_lsm_k(const float* __restrict__ z,
                                                 const float* __restrict__ sums, const float* __restrict__ sumsq,
                                                 const float* __restrict__ gamma, const float* __restrict__ beta,
                                                 const float* __restrict__ w,
                                                 const float* __restrict__ b, float* __restrict__ out,
                                                 int N, float invN) {
  __shared__ float ssc[64], ssh[64];
  if (threadIdx.x < 64) {
    int c = threadIdx.x;
    float mean = sums[c] * invN;
    float var = sumsq[c] * invN - mean * mean;
    float rs = rsqrtf(var + BN_EPS);
    float sc = gamma[c] * rs;
    ssc[c] = sc;
    ssh[c] = beta[c] - mean * sc;
  }
  __syncthreads();
  int n = blockIdx.x * 256 + threadIdx.x;
  if (n >= N) return;
  float o[40];
#pragma unroll
  for (int c = 0; c < 40; ++c) o[c] = b[c];
  const float* zr = z + (size_t)n * 64;
  for (int k = 0; k < 64; ++k) {
    float v = fmaxf(fmaf(zr[k], ssc[k], ssh[k]), 0.f);
#pragma unroll
    for (int c = 0; c < 40; ++c) o[c] = fmaf(v, w[k * 40 + c], o[c]);
  }
  float mx = o[0];
#pragma unroll
  for (int c = 1; c < 40; ++c) mx = fmaxf(mx, o[c]);
  float s = 0.f;
#pragma unroll
  for (int c = 0; c < 40; ++c) s += __expf(o[c] - mx);
  float ls = __logf(s);
  float* orow = out + (size_t)n * 40;
#pragma unroll
  for (int c = 0; c < 40; ++c) orow[c] = o[c] - mx - ls;
}

// ---------------- launch ----------------
static inline char* al16(char* p) { return (char*)(((size_t)p + 15) & ~(size_t)15); }

extern "C" void kernel_launch(void* const* d_in, const int* in_sizes, int n_in,
                              void* d_out, int out_size, void* d_ws, size_t ws_size,
                              hipStream_t stream) {
  const float* x     = (const float*)d_in[0];
  const int*   eidx  = (const int*)d_in[1];
  const float* W1s   = (const float*)d_in[2];
  const float* W1d   = (const float*)d_in[3];
  const float* att1s = (const float*)d_in[4];
  const float* att1d = (const float*)d_in[5];
  const float* b1    = (const float*)d_in[6];
  const float* W2s   = (const float*)d_in[7];
  const float* W2d   = (const float*)d_in[8];
  const float* att2s = (const float*)d_in[9];
  const float* att2d = (const float*)d_in[10];
  const float* b2    = (const float*)d_in[11];
  const float* fc1w  = (const float*)d_in[12];
  const float* fc1b  = (const float*)d_in[13];
  const float* gamma = (const float*)d_in[14];
  const float* beta  = (const float*)d_in[15];
  const float* fc2w  = (const float*)d_in[16];
  const float* fc2b  = (const float*)d_in[17];
  float* out = (float*)d_out;

  const int N  = in_sizes[0] / 256;
  const int E  = in_sizes[1] / 2;
  const int ET = E + N;

  // workspace layout — deg/sums/sumsq contiguous at front for a single memset
  char* p = (char*)d_ws;
  int* deg      = (int*)p;     p += (size_t)N * 4;
  float* sums   = (float*)p;   p += 64 * 4;
  float* sumsq  = (float*)p;   p += 64 * 4;
  unsigned short* bhA = (unsigned short*)p; p += (size_t)N * 128 * 2;
  _Float16* hAh = (_Float16*)p;  p += (size_t)N * 128 * 2;
  _Float16* hAl = (_Float16*)p;  p += (size_t)N * 128 * 2;
  float* hF = (float*)p;         p += (size_t)N * 64 * 4;
  int* rowstart = (int*)p;     p += (size_t)(N + 1) * 4;
  int* cursor   = (int*)p;     p += (size_t)N * 4;
  int* csr_src  = (int*)p;     p += (size_t)ET * 4;
  float* a_src  = (float*)p;   p += (size_t)N * 4;
  float* a_dst  = (float*)p;   p += (size_t)N * 4;
  float* a_dst2 = (float*)p;   p += (size_t)N * 4;
  float* wvd1   = (float*)p;   p += 256 * 4;
  float* wvd2   = (float*)p;   p += 128 * 4;
  float* wvs1   = (float*)p;   p += 256 * 4;
  float* wvs2   = (float*)p;   p += 128 * 4;
  int* bsum     = (int*)p;     p += 256 * 4;
  p = al16(p);
  _Float16* B1h = (_Float16*)p; p += (size_t)256 * 128 * 2;
  _Float16* B1l = (_Float16*)p; p += (size_t)256 * 128 * 2;
  _Float16* B2h = (_Float16*)p; p += (size_t)128 * 128 * 2;
  _Float16* B2l = (_Float16*)p; p += (size_t)128 * 128 * 2;
  _Float16* Bfh = (_Float16*)p; p += (size_t)128 * 64 * 2;
  _Float16* Bfl = (_Float16*)p; p += (size_t)128 * 64 * 2;

  const int* esrc = eidx;
  const int* edst = eidx + E;

  // one memset zeroes deg + sums + sumsq
  hipMemsetAsync(deg, 0, (size_t)N * 4 + 512, stream);

  deg_count_k<<<(ET + 255) / 256, 256, 0, stream>>>(edst, E, N, deg);
  int nb = (N + 1023) / 1024;
  scan1_k<<<nb, 1024, 0, stream>>>(deg, N, rowstart, bsum);
  scan3_k<<<(N + 255) / 256, 256, 0, stream>>>(rowstart, bsum, N, nb, ET, cursor);
  {
    const int NR = 8;
    int step = (N + NR - 1) / NR;
    for (int r = 0; r < NR; ++r) {
      int d0 = r * step;
      int d1 = d0 + step < N ? d0 + step : N;
      scatter_range_k<<<(ET + 255) / 256, 256, 0, stream>>>(esrc, edst, E, N, d0, d1, cursor, csr_src);
    }
  }

  // fused weight prep: 3 B-splits + 4 fold-matvecs in one dispatch
  prep_k<<<220, 256, 0, stream>>>(W1s, W2s, fc1w, W1d, att1d, W2d, att2d, att1s, att2s,
                                  B1h, B1l, B2h, B2l, Bfh, Bfl, wvd1, wvd2, wvs1, wvs2);

  const int gdk = (N + 63) / 64;

  // ---- GAT layer 1: staged GEMM emits bf16 h + fused a_src (x.wvs1) + a_dst (x.wvd1) ----
  gemm_sk<256, 128, false><<<gdk, 256, 0, stream>>>(x, nullptr, nullptr, B1h, B1l,
                                                    nullptr, bhA, wvs1, a_src, wvd1, a_dst, N, nullptr);
  gat_agg_k<<<(N + 3) / 4, 256, 0, stream>>>(bhA, a_src, a_dst, rowstart, csr_src, b1,
                                             hAh, hAl, wvd2, a_dst2, N);

  // ---- GAT layer 2 (A pre-split f16; a_src2 = hA.wvs2 fused; a_dst2 fused in L1 agg) ----
  gemm_sk<128, 128, true><<<gdk, 256, 0, stream>>>(nullptr, hAh, hAl, B2h, B2l,
                                                   nullptr, bhA, wvs2, a_src, nullptr, nullptr, N, nullptr);
  gat_agg_k<<<(N + 3) / 4, 256, 0, stream>>>(bhA, a_src, a_dst2, rowstart, csr_src, b2,
                                             hAh, hAl, nullptr, nullptr, N);

  // ---- FC1 -> BN-stats -> fused BN+FC2+log_softmax ----
  gemm_sk<128, 64, true><<<gdk, 256, 0, stream>>>(nullptr, hAh, hAl, Bfh, Bfl,
                                                  hF, nullptr, nullptr, nullptr, nullptr, nullptr, N, fc1b);
  bn_stats_k<<<512, 256, 0, stream>>>(hF, N, sums, sumsq);
  fc2_lsm_k<<<(N + 255) / 256, 256, 0, stream>>>(hF, sums, sumsq, gamma, beta, fc2w, fc2b, out,
                                                 N, 1.0f / (float)N);
}